// Round 1
// baseline (271.403 us; speedup 1.0000x reference)
//
#include <hip/hip_runtime.h>

#define NHEADS 16
#define EMB 1024
#define HDIM 64
#define SEQ 2048
#define BATCH 4

typedef unsigned short u16;
typedef __attribute__((ext_vector_type(8))) __bf16 bf16x8;
typedef __attribute__((ext_vector_type(4))) float f32x4;

__device__ __forceinline__ u16 f2bf(float f) {
  union { float f; unsigned u; } v; v.f = f;
  unsigned r = v.u + 0x7fffu + ((v.u >> 16) & 1u);
  return (u16)(r >> 16);
}

// ---------------- elementwise f32 -> bf16 ----------------
__global__ __launch_bounds__(256) void k_cvt(const float* __restrict__ in,
                                             u16* __restrict__ out, int n4) {
  int i = blockIdx.x * 256 + threadIdx.x;
  if (i >= n4) return;
  f32x4 v = *(const f32x4*)(in + (size_t)i * 4);
  uint2 o;
  o.x = (unsigned)f2bf(v[0]) | ((unsigned)f2bf(v[1]) << 16);
  o.y = (unsigned)f2bf(v[2]) | ((unsigned)f2bf(v[3]) << 16);
  *(uint2*)(out + (size_t)i * 4) = o;
}

// ---------------- pack Wq/Wk/Wv -> Wt[n=(m,h,d)][k=e] bf16 (transposed) ----------------
__global__ __launch_bounds__(256) void k_packw(const float* __restrict__ Wq,
                                               const float* __restrict__ Wk,
                                               const float* __restrict__ Wv,
                                               u16* __restrict__ Wt) {
  const int mh = blockIdx.x;        // 0..47 = mtx*16+h
  const int e0 = blockIdx.y * 64;
  const int mtx = mh >> 4, h = mh & 15;
  const float* W = (mtx == 0 ? Wq : (mtx == 1 ? Wk : Wv)) + (size_t)h * EMB * HDIM;
  __shared__ u16 sT[64][65];
  const int t = threadIdx.x;
  {
    int e = t >> 2, d0 = (t & 3) * 16;
#pragma unroll
    for (int jj = 0; jj < 4; jj++) {
      f32x4 v = *(const f32x4*)(W + (size_t)(e0 + e) * HDIM + d0 + jj * 4);
#pragma unroll
      for (int kk = 0; kk < 4; kk++) sT[e][d0 + jj * 4 + kk] = f2bf(v[kk]);
    }
  }
  __syncthreads();
  {
    int d = t >> 2, eb = (t & 3) * 16;
#pragma unroll
    for (int j = 0; j < 16; j++)
      Wt[(size_t)(mh * 64 + d) * EMB + e0 + eb + j] = sT[eb + j][d];
  }
}

// ---------------- GEMM1: Xb[8192x1024] x Wt -> Q,K,V [B,H,S,D] bf16 ----------------
__global__ __launch_bounds__(256) void k_gemm_qkv(const u16* __restrict__ Xb,
                                                  const u16* __restrict__ Wt,
                                                  u16* __restrict__ Q,
                                                  u16* __restrict__ K,
                                                  u16* __restrict__ V) {
  const int m0 = blockIdx.x * 128;
  const int n0 = blockIdx.y * 128;
  const int t = threadIdx.x;
  const int wave = t >> 6, lane = t & 63, lr = lane & 15, lg = lane >> 4;
  const int wr = (wave >> 1) * 64, wc = (wave & 1) * 64;

  __shared__ __align__(16) char sA[128 * 128];
  __shared__ __align__(16) char sB[128 * 128];

  const f32x4 fz = {0.f, 0.f, 0.f, 0.f};
  f32x4 acc[4][4];
#pragma unroll
  for (int i = 0; i < 4; i++)
#pragma unroll
    for (int j = 0; j < 4; j++) acc[i][j] = fz;

  for (int k0 = 0; k0 < EMB; k0 += 64) {
#pragma unroll
    for (int i = 0; i < 4; i++) {
      int c = t + i * 256;
      int row = c >> 3;
      int off = (c & 7) * 16;
      int sw = off ^ ((row & 7) << 4);
      *(bf16x8*)(sA + row * 128 + sw) =
          *(const bf16x8*)(Xb + (size_t)(m0 + row) * EMB + k0 + (off >> 1));
      *(bf16x8*)(sB + row * 128 + sw) =
          *(const bf16x8*)(Wt + (size_t)(n0 + row) * EMB + k0 + (off >> 1));
    }
    __syncthreads();
    bf16x8 af[4][2], bfr[4][2];
#pragma unroll
    for (int mf = 0; mf < 4; mf++)
#pragma unroll
      for (int kf = 0; kf < 2; kf++) {
        int row = wr + mf * 16 + lr;
        af[mf][kf] = *(const bf16x8*)(sA + row * 128 + ((kf * 64 + lg * 16) ^ ((row & 7) << 4)));
      }
#pragma unroll
    for (int nf = 0; nf < 4; nf++)
#pragma unroll
      for (int kf = 0; kf < 2; kf++) {
        int row = wc + nf * 16 + lr;
        bfr[nf][kf] = *(const bf16x8*)(sB + row * 128 + ((kf * 64 + lg * 16) ^ ((row & 7) << 4)));
      }
#pragma unroll
    for (int kf = 0; kf < 2; kf++)
#pragma unroll
      for (int mf = 0; mf < 4; mf++)
#pragma unroll
        for (int nf = 0; nf < 4; nf++)
          acc[mf][nf] = __builtin_amdgcn_mfma_f32_16x16x32_bf16(af[mf][kf], bfr[nf][kf], acc[mf][nf], 0, 0, 0);
    __syncthreads();
  }

  const int b = m0 >> 11;
  const int s0 = m0 & 2047;
#pragma unroll
  for (int mf = 0; mf < 4; mf++)
#pragma unroll
    for (int nf = 0; nf < 4; nf++)
#pragma unroll
      for (int r = 0; r < 4; r++) {
        int row = wr + mf * 16 + lg * 4 + r;          // D row = 4*(lane>>4)+reg
        int n = n0 + wc + nf * 16 + lr;               // D col = lane&15
        int mtx = n >> 10, h = (n >> 6) & 15, d = n & 63;
        u16* dst = (mtx == 0 ? Q : (mtx == 1 ? K : V));
        dst[((size_t)(b * NHEADS + h) * SEQ + s0 + row) * HDIM + d] = f2bf(acc[mf][nf][r]);
      }
}

// ---------------- causal flash attention ----------------
__global__ __launch_bounds__(256) void k_attn(const u16* __restrict__ Q,
                                              const u16* __restrict__ K,
                                              const u16* __restrict__ V,
                                              u16* __restrict__ Cc) {
  const int bh = blockIdx.x;   // 0..63
  const int qt = blockIdx.y;   // 0..15
  const int b = bh >> 4, h = bh & 15;
  const int t = threadIdx.x;
  const int wave = t >> 6, lane = t & 63, lr = lane & 15, lg = lane >> 4;
  const size_t base = (size_t)bh * SEQ * HDIM;

  __shared__ __align__(16) char sK[64 * 128];
  __shared__ __align__(16) char sV[64 * 128];
  __shared__ __align__(16) char sP[128 * 128];

  // stage Q tile into sP, pull A-fragments to registers
#pragma unroll
  for (int i = 0; i < 4; i++) {
    int c = t + i * 256;
    int row = c >> 3, off = (c & 7) * 16;
    *(bf16x8*)(sP + row * 128 + (off ^ ((row & 7) << 4))) =
        *(const bf16x8*)(Q + base + (size_t)(qt * 128 + row) * HDIM + (off >> 1));
  }
  __syncthreads();
  bf16x8 qf[2][2];
#pragma unroll
  for (int mf = 0; mf < 2; mf++)
#pragma unroll
    for (int kf = 0; kf < 2; kf++) {
      int row = wave * 32 + mf * 16 + lr;
      qf[mf][kf] = *(const bf16x8*)(sP + row * 128 + ((kf * 64 + lg * 16) ^ ((row & 7) << 4)));
    }

  const f32x4 fz = {0.f, 0.f, 0.f, 0.f};
  f32x4 o[2][4];
#pragma unroll
  for (int i = 0; i < 2; i++)
#pragma unroll
    for (int j = 0; j < 4; j++) o[i][j] = fz;
  float mst[2][4], lst[2][4];
#pragma unroll
  for (int i = 0; i < 2; i++)
#pragma unroll
    for (int j = 0; j < 4; j++) { mst[i][j] = -1e30f; lst[i][j] = 0.f; }

  const int nsteps = 2 * qt + 2;
  for (int step = 0; step < nsteps; step++) {
    const int k0 = step * 64;
    __syncthreads();
    // stage K tile [kv][d]
#pragma unroll
    for (int i = 0; i < 2; i++) {
      int c = t + i * 256;
      int row = c >> 3, off = (c & 7) * 16;
      *(bf16x8*)(sK + row * 128 + (off ^ ((row & 7) << 4))) =
          *(const bf16x8*)(K + base + (size_t)(k0 + row) * HDIM + (off >> 1));
    }
    // stage V transposed [d][kv]
    {
      int kv = t >> 2, d0 = (t & 3) * 16;
      bf16x8 v0 = *(const bf16x8*)(V + base + (size_t)(k0 + kv) * HDIM + d0);
      bf16x8 v1 = *(const bf16x8*)(V + base + (size_t)(k0 + kv) * HDIM + d0 + 8);
#pragma unroll
      for (int j = 0; j < 8; j++) {
        int d = d0 + j;
        *(__bf16*)(sV + d * 128 + ((kv * 2) ^ ((d & 7) << 4))) = v0[j];
        int d2 = d0 + 8 + j;
        *(__bf16*)(sV + d2 * 128 + ((kv * 2) ^ ((d2 & 7) << 4))) = v1[j];
      }
    }
    __syncthreads();

    // QK^T
    f32x4 s[2][4];
#pragma unroll
    for (int i = 0; i < 2; i++)
#pragma unroll
      for (int j = 0; j < 4; j++) s[i][j] = fz;
    bf16x8 kfr[4][2];
#pragma unroll
    for (int nf = 0; nf < 4; nf++)
#pragma unroll
      for (int kf = 0; kf < 2; kf++) {
        int row = nf * 16 + lr;  // kv
        kfr[nf][kf] = *(const bf16x8*)(sK + row * 128 + ((kf * 64 + lg * 16) ^ ((row & 7) << 4)));
      }
#pragma unroll
    for (int kf = 0; kf < 2; kf++)
#pragma unroll
      for (int mf = 0; mf < 2; mf++)
#pragma unroll
        for (int nf = 0; nf < 4; nf++)
          s[mf][nf] = __builtin_amdgcn_mfma_f32_16x16x32_bf16(qf[mf][kf], kfr[nf][kf], s[mf][nf], 0, 0, 0);

    // online softmax (rows live in D-layout: row = 4*lg + r, col = lane&15 + 16*nf)
#pragma unroll
    for (int mf = 0; mf < 2; mf++)
#pragma unroll
      for (int r = 0; r < 4; r++) {
        int rowl = wave * 32 + mf * 16 + lg * 4 + r;
        int rowg = qt * 128 + rowl;
        float vals[4];
#pragma unroll
        for (int nf = 0; nf < 4; nf++) {
          int colg = k0 + nf * 16 + lr;
          float sv = s[mf][nf][r] * 0.125f;
          vals[nf] = (colg > rowg) ? -1e30f : sv;
        }
        float mx = fmaxf(fmaxf(vals[0], vals[1]), fmaxf(vals[2], vals[3]));
#pragma unroll
        for (int offm = 1; offm < 16; offm <<= 1) mx = fmaxf(mx, __shfl_xor(mx, offm));
        float mnew = fmaxf(mst[mf][r], mx);
        float alpha = __expf(mst[mf][r] - mnew);
        float rs = 0.f;
#pragma unroll
        for (int nf = 0; nf < 4; nf++) {
          float p = __expf(vals[nf] - mnew);
          rs += p;
          int col = nf * 16 + lr;
          *(__bf16*)(sP + rowl * 128 + ((col * 2) ^ ((rowl & 7) << 4))) = (__bf16)p;
        }
#pragma unroll
        for (int offm = 1; offm < 16; offm <<= 1) rs += __shfl_xor(rs, offm);
        lst[mf][r] = lst[mf][r] * alpha + rs;
        mst[mf][r] = mnew;
#pragma unroll
        for (int nf = 0; nf < 4; nf++) o[mf][nf][r] *= alpha;
      }

    // PV (each wave reads only its own 32 P rows -> no barrier needed; compiler
    // orders the wave-local ds_write->ds_read via lgkmcnt)
    bf16x8 pf[2][2], vf[4][2];
#pragma unroll
    for (int mf = 0; mf < 2; mf++)
#pragma unroll
      for (int kf = 0; kf < 2; kf++) {
        int row = wave * 32 + mf * 16 + lr;
        pf[mf][kf] = *(const bf16x8*)(sP + row * 128 + ((kf * 64 + lg * 16) ^ ((row & 7) << 4)));
      }
#pragma unroll
    for (int nf = 0; nf < 4; nf++)
#pragma unroll
      for (int kf = 0; kf < 2; kf++) {
        int row = nf * 16 + lr;  // d
        vf[nf][kf] = *(const bf16x8*)(sV + row * 128 + ((kf * 64 + lg * 16) ^ ((row & 7) << 4)));
      }
#pragma unroll
    for (int kf = 0; kf < 2; kf++)
#pragma unroll
      for (int mf = 0; mf < 2; mf++)
#pragma unroll
        for (int nf = 0; nf < 4; nf++)
          o[mf][nf] = __builtin_amdgcn_mfma_f32_16x16x32_bf16(pf[mf][kf], vf[nf][kf], o[mf][nf], 0, 0, 0);
  }

  // normalize + write concat ctx [B,S,H*D] bf16
#pragma unroll
  for (int mf = 0; mf < 2; mf++)
#pragma unroll
    for (int r = 0; r < 4; r++) {
      int rowl = wave * 32 + mf * 16 + lg * 4 + r;
      int sg = qt * 128 + rowl;
      float inv = 1.0f / lst[mf][r];
#pragma unroll
      for (int nf = 0; nf < 4; nf++) {
        int d = nf * 16 + lr;
        Cc[((size_t)b * SEQ + sg) * (NHEADS * HDIM) + h * HDIM + d] = f2bf(o[mf][nf][r] * inv);
      }
    }
}

// ---------------- GEMM2: ctx[8192x1024] x Wo^T + bo -> out fp32 ----------------
__global__ __launch_bounds__(256) void k_gemm_out(const u16* __restrict__ Cc,
                                                  const u16* __restrict__ Wob,
                                                  const float* __restrict__ bo,
                                                  float* __restrict__ out) {
  const int m0 = blockIdx.x * 128;
  const int n0 = blockIdx.y * 128;
  const int t = threadIdx.x;
  const int wave = t >> 6, lane = t & 63, lr = lane & 15, lg = lane >> 4;
  const int wr = (wave >> 1) * 64, wc = (wave & 1) * 64;

  __shared__ __align__(16) char sA[128 * 128];
  __shared__ __align__(16) char sB[128 * 128];

  const f32x4 fz = {0.f, 0.f, 0.f, 0.f};
  f32x4 acc[4][4];
#pragma unroll
  for (int i = 0; i < 4; i++)
#pragma unroll
    for (int j = 0; j < 4; j++) acc[i][j] = fz;

  for (int k0 = 0; k0 < EMB; k0 += 64) {
#pragma unroll
    for (int i = 0; i < 4; i++) {
      int c = t + i * 256;
      int row = c >> 3;
      int off = (c & 7) * 16;
      int sw = off ^ ((row & 7) << 4);
      *(bf16x8*)(sA + row * 128 + sw) =
          *(const bf16x8*)(Cc + (size_t)(m0 + row) * EMB + k0 + (off >> 1));
      *(bf16x8*)(sB + row * 128 + sw) =
          *(const bf16x8*)(Wob + (size_t)(n0 + row) * EMB + k0 + (off >> 1));
    }
    __syncthreads();
    bf16x8 af[4][2], bfr[4][2];
#pragma unroll
    for (int mf = 0; mf < 4; mf++)
#pragma unroll
      for (int kf = 0; kf < 2; kf++) {
        int row = wr + mf * 16 + lr;
        af[mf][kf] = *(const bf16x8*)(sA + row * 128 + ((kf * 64 + lg * 16) ^ ((row & 7) << 4)));
      }
#pragma unroll
    for (int nf = 0; nf < 4; nf++)
#pragma unroll
      for (int kf = 0; kf < 2; kf++) {
        int row = wc + nf * 16 + lr;
        bfr[nf][kf] = *(const bf16x8*)(sB + row * 128 + ((kf * 64 + lg * 16) ^ ((row & 7) << 4)));
      }
#pragma unroll
    for (int kf = 0; kf < 2; kf++)
#pragma unroll
      for (int mf = 0; mf < 4; mf++)
#pragma unroll
        for (int nf = 0; nf < 4; nf++)
          acc[mf][nf] = __builtin_amdgcn_mfma_f32_16x16x32_bf16(af[mf][kf], bfr[nf][kf], acc[mf][nf], 0, 0, 0);
    __syncthreads();
  }

  float bv[4];
#pragma unroll
  for (int nf = 0; nf < 4; nf++) bv[nf] = bo[n0 + wc + nf * 16 + lr];
#pragma unroll
  for (int mf = 0; mf < 4; mf++)
#pragma unroll
    for (int nf = 0; nf < 4; nf++)
#pragma unroll
      for (int r = 0; r < 4; r++) {
        int row = wr + mf * 16 + lg * 4 + r;
        int n = n0 + wc + nf * 16 + lr;
        out[(size_t)(m0 + row) * EMB + n] = acc[mf][nf][r] + bv[nf];
      }
}

extern "C" void kernel_launch(void* const* d_in, const int* in_sizes, int n_in,
                              void* d_out, int out_size, void* d_ws, size_t ws_size,
                              hipStream_t stream) {
  const float* x  = (const float*)d_in[0];
  const float* Wq = (const float*)d_in[1];
  const float* Wk = (const float*)d_in[2];
  const float* Wv = (const float*)d_in[3];
  const float* Wo = (const float*)d_in[4];
  const float* bo = (const float*)d_in[5];
  float* out = (float*)d_out;

  char* ws = (char*)d_ws;
  const size_t SZ_XB  = (size_t)8192 * 1024 * 2;   // 16 MB
  const size_t SZ_WT  = (size_t)3072 * 1024 * 2;   // 6 MB
  const size_t SZ_WOB = (size_t)1024 * 1024 * 2;   // 2 MB
  const size_t SZ_QKV = (size_t)64 * 2048 * 64 * 2;// 16 MB each
  u16* Xb  = (u16*)(ws);
  u16* Wt  = (u16*)(ws + SZ_XB);
  u16* Wob = (u16*)(ws + SZ_XB + SZ_WT);
  u16* Qb  = (u16*)(ws + SZ_XB + SZ_WT + SZ_WOB);
  u16* Kb  = (u16*)(ws + SZ_XB + SZ_WT + SZ_WOB + SZ_QKV);
  u16* Vb  = (u16*)(ws + SZ_XB + SZ_WT + SZ_WOB + 2 * SZ_QKV);
  u16* Cc  = (u16*)(ws + SZ_XB + SZ_WT + SZ_WOB + 3 * SZ_QKV);

  k_cvt<<<8192, 256, 0, stream>>>(x, Xb, 2097152);          // x: 8.39M elems / 4
  k_cvt<<<1024, 256, 0, stream>>>(Wo, Wob, 262144);         // Wo: 1.05M elems / 4
  k_packw<<<dim3(48, 16), 256, 0, stream>>>(Wq, Wk, Wv, Wt);
  k_gemm_qkv<<<dim3(64, 24), 256, 0, stream>>>(Xb, Wt, Qb, Kb, Vb);
  k_attn<<<dim3(64, 16), 256, 0, stream>>>(Qb, Kb, Vb, Cc);
  k_gemm_out<<<dim3(64, 8), 256, 0, stream>>>(Cc, Wob, bo, out);
}

// Round 2
// 174.144 us; speedup vs baseline: 1.5585x; 1.5585x over previous
//
#include <hip/hip_runtime.h>

#define NHEADS 16
#define EMB 1024
#define HDIM 64
#define SEQ 2048
#define BATCH 4

typedef unsigned short u16;
typedef __attribute__((ext_vector_type(8))) __bf16 bf16x8;
typedef __attribute__((ext_vector_type(4))) float f32x4;

#if __has_builtin(__builtin_amdgcn_exp2f)
#define EXP2(x) __builtin_amdgcn_exp2f(x)
#else
#define EXP2(x) __expf((x)*0.69314718056f)
#endif
#define CL2E 0.18033688011112042f  // 0.125 * log2(e)

__device__ __forceinline__ u16 f2bf(float f) {
  union { float f; unsigned u; } v; v.f = f;
  unsigned r = v.u + 0x7fffu + ((v.u >> 16) & 1u);
  return (u16)(r >> 16);
}
__device__ __forceinline__ unsigned pk2bf(float a, float b) {
  union { __bf16 h[2]; unsigned u; } x;
  x.h[0] = (__bf16)a; x.h[1] = (__bf16)b; return x.u;
}
__device__ __forceinline__ void gl16(const void* g, void* l) {
  __builtin_amdgcn_global_load_lds(
      (const __attribute__((address_space(1))) unsigned*)g,
      (__attribute__((address_space(3))) unsigned*)l, 16, 0, 0);
}

// ---------------- elementwise f32 -> bf16 ----------------
__global__ __launch_bounds__(256) void k_cvt(const float* __restrict__ in,
                                             u16* __restrict__ out, int n4) {
  int i = blockIdx.x * 256 + threadIdx.x;
  if (i >= n4) return;
  f32x4 v = *(const f32x4*)(in + (size_t)i * 4);
  uint2 o;
  o.x = (unsigned)f2bf(v[0]) | ((unsigned)f2bf(v[1]) << 16);
  o.y = (unsigned)f2bf(v[2]) | ((unsigned)f2bf(v[3]) << 16);
  *(uint2*)(out + (size_t)i * 4) = o;
}

// ---------------- pack Wq/Wk/Wv -> Wt[n=(m,h,d)][k=e] bf16 (transposed) ----------------
__global__ __launch_bounds__(256) void k_packw(const float* __restrict__ Wq,
                                               const float* __restrict__ Wk,
                                               const float* __restrict__ Wv,
                                               u16* __restrict__ Wt) {
  const int mh = blockIdx.x;        // 0..47 = mtx*16+h
  const int e0 = blockIdx.y * 64;
  const int mtx = mh >> 4, h = mh & 15;
  const float* W = (mtx == 0 ? Wq : (mtx == 1 ? Wk : Wv)) + (size_t)h * EMB * HDIM;
  __shared__ u16 sT[64][65];
  const int t = threadIdx.x;
  {
    int e = t >> 2, d0 = (t & 3) * 16;
#pragma unroll
    for (int jj = 0; jj < 4; jj++) {
      f32x4 v = *(const f32x4*)(W + (size_t)(e0 + e) * HDIM + d0 + jj * 4);
#pragma unroll
      for (int kk = 0; kk < 4; kk++) sT[e][d0 + jj * 4 + kk] = f2bf(v[kk]);
    }
  }
  __syncthreads();
  {
    int d = t >> 2, eb = (t & 3) * 16;
#pragma unroll
    for (int j = 0; j < 16; j++)
      Wt[(size_t)(mh * 64 + d) * EMB + e0 + eb + j] = sT[eb + j][d];
  }
}

// ---------------- GEMM1: Xb[8192x1024] x Wt -> Q,K,V [B,H,S,D] bf16 ----------------
__global__ __launch_bounds__(256) void k_gemm_qkv(const u16* __restrict__ Xb,
                                                  const u16* __restrict__ Wt,
                                                  u16* __restrict__ Q,
                                                  u16* __restrict__ K,
                                                  u16* __restrict__ V) {
  const int m0 = blockIdx.x * 128;
  const int n0 = blockIdx.y * 128;
  const int t = threadIdx.x;
  const int wave = t >> 6, lane = t & 63, lr = lane & 15, lg = lane >> 4;
  const int wr = (wave >> 1) * 64, wc = (wave & 1) * 64;

  __shared__ __align__(16) char sA[128 * 128];
  __shared__ __align__(16) char sB[128 * 128];

  const f32x4 fz = {0.f, 0.f, 0.f, 0.f};
  f32x4 acc[4][4];
#pragma unroll
  for (int i = 0; i < 4; i++)
#pragma unroll
    for (int j = 0; j < 4; j++) acc[i][j] = fz;

  for (int k0 = 0; k0 < EMB; k0 += 64) {
    // global_load_lds staging, pre-swizzled global source (rule #21)
#pragma unroll
    for (int i = 0; i < 4; i++) {
      int rb = wave * 32 + i * 8;
      int row = rb + (lane >> 3);
      int gc = (lane & 7) ^ (row & 7);
      gl16(Xb + (size_t)(m0 + row) * EMB + k0 + gc * 8, sA + rb * 128);
      gl16(Wt + (size_t)(n0 + row) * EMB + k0 + gc * 8, sB + rb * 128);
    }
    __syncthreads();
    bf16x8 af[4][2], bfr[4][2];
#pragma unroll
    for (int mf = 0; mf < 4; mf++)
#pragma unroll
      for (int kf = 0; kf < 2; kf++) {
        int row = wr + mf * 16 + lr;
        af[mf][kf] = *(const bf16x8*)(sA + row * 128 + ((kf * 64 + lg * 16) ^ ((row & 7) << 4)));
      }
#pragma unroll
    for (int nf = 0; nf < 4; nf++)
#pragma unroll
      for (int kf = 0; kf < 2; kf++) {
        int row = wc + nf * 16 + lr;
        bfr[nf][kf] = *(const bf16x8*)(sB + row * 128 + ((kf * 64 + lg * 16) ^ ((row & 7) << 4)));
      }
#pragma unroll
    for (int kf = 0; kf < 2; kf++)
#pragma unroll
      for (int mf = 0; mf < 4; mf++)
#pragma unroll
        for (int nf = 0; nf < 4; nf++)
          acc[mf][nf] = __builtin_amdgcn_mfma_f32_16x16x32_bf16(af[mf][kf], bfr[nf][kf], acc[mf][nf], 0, 0, 0);
    __syncthreads();
  }

  const int b = m0 >> 11;
  const int s0 = m0 & 2047;
#pragma unroll
  for (int mf = 0; mf < 4; mf++)
#pragma unroll
    for (int nf = 0; nf < 4; nf++)
#pragma unroll
      for (int r = 0; r < 4; r++) {
        int row = wr + mf * 16 + lg * 4 + r;
        int n = n0 + wc + nf * 16 + lr;
        int mtx = n >> 10, h = (n >> 6) & 15, d = n & 63;
        u16* dst = (mtx == 0 ? Q : (mtx == 1 ? K : V));
        dst[((size_t)(b * NHEADS + h) * SEQ + s0 + row) * HDIM + d] = f2bf(acc[mf][nf][r]);
      }
}

// ---------------- causal flash attention (swapped QK^T / transposed PV) ----------------
__global__ __launch_bounds__(256, 3) void k_attn(const u16* __restrict__ Q,
                                                 const u16* __restrict__ K,
                                                 const u16* __restrict__ V,
                                                 u16* __restrict__ Cc) {
  const int bh = blockIdx.x;                 // 0..63
  const int qt = 15 - (int)blockIdx.y;       // LPT: heaviest q-tiles dispatched first
  const int b = bh >> 4, h = bh & 15;
  const int t = threadIdx.x;
  const int wq = t >> 6, lane = t & 63, lr = lane & 15, lg = lane >> 4;
  const size_t base = (size_t)bh * SEQ * HDIM;

  __shared__ __align__(16) char sK[64 * 128];
  __shared__ __align__(16) char sV[64 * 128];
  __shared__ __align__(16) char sP[128 * 128];

  // ---- stage Q tile (swizzled, via global_load_lds) ----
#pragma unroll
  for (int i = 0; i < 4; i++) {
    int rb = wq * 32 + i * 8;
    int row = rb + (lane >> 3);
    int gc = (lane & 7) ^ (row & 7);
    gl16(Q + base + (size_t)(qt * 128 + row) * HDIM + gc * 8, sP + rb * 128);
  }
  __syncthreads();
  bf16x8 qf[2][2];
#pragma unroll
  for (int q2 = 0; q2 < 2; q2++)
#pragma unroll
    for (int kf = 0; kf < 2; kf++) {
      int row = wq * 32 + q2 * 16 + lr;
      qf[q2][kf] = *(const bf16x8*)(sP + row * 128 + ((kf * 64 + lg * 16) ^ ((row & 7) << 4)));
    }

  const f32x4 fz = {0.f, 0.f, 0.f, 0.f};
  f32x4 ot[4][2];  // O^T frags: row d = df*16+4*lg+r, col q = lr
#pragma unroll
  for (int df = 0; df < 4; df++)
#pragma unroll
    for (int q2 = 0; q2 < 2; q2++) ot[df][q2] = fz;
  float m_[2] = {-1e30f, -1e30f}, l_[2] = {0.f, 0.f};

  const int nsteps = 2 * qt + 2;
  for (int step = 0; step < nsteps; step++) {
    const int k0 = step * 64;
    __syncthreads();
    // K stage via global_load_lds (pre-swizzled source)
#pragma unroll
    for (int i = 0; i < 2; i++) {
      int rb = wq * 16 + i * 8;
      int row = rb + (lane >> 3);
      int gc = (lane & 7) ^ (row & 7);
      gl16(K + base + (size_t)(k0 + row) * HDIM + gc * 8, sK + rb * 128);
    }
    // V transposed [d][kv], kv=lane mapping -> 2-way (free) bank pattern
    {
      const int kv = lane, d0 = wq * 16;
      const u16* vp = V + base + (size_t)(k0 + kv) * HDIM + d0;
      bf16x8 v0 = *(const bf16x8*)vp;
      bf16x8 v1 = *(const bf16x8*)(vp + 8);
#pragma unroll
      for (int j = 0; j < 8; j++) {
        int d = d0 + j, d2 = d0 + 8 + j;
        *(__bf16*)(sV + d * 128 + ((kv * 2) ^ ((d & 7) << 4))) = v0[j];
        *(__bf16*)(sV + d2 * 128 + ((kv * 2) ^ ((d2 & 7) << 4))) = v1[j];
      }
    }
    __syncthreads();

    // ---- S^T = K · Q^T  (D: col=q=lr, row=kv=4*lg+r) ----
    f32x4 st[4][2];
#pragma unroll
    for (int kvf = 0; kvf < 4; kvf++)
#pragma unroll
      for (int q2 = 0; q2 < 2; q2++) st[kvf][q2] = fz;
#pragma unroll
    for (int kf = 0; kf < 2; kf++) {
      bf16x8 kfr[4];
#pragma unroll
      for (int kvf = 0; kvf < 4; kvf++) {
        int row = kvf * 16 + lr;
        kfr[kvf] = *(const bf16x8*)(sK + row * 128 + ((kf * 64 + lg * 16) ^ ((row & 7) << 4)));
      }
#pragma unroll
      for (int kvf = 0; kvf < 4; kvf++)
#pragma unroll
        for (int q2 = 0; q2 < 2; q2++)
          st[kvf][q2] = __builtin_amdgcn_mfma_f32_16x16x32_bf16(kfr[kvf], qf[q2][kf], st[kvf][q2], 0, 0, 0);
    }

    // ---- online softmax, row-local (q = lr) ----
    const bool diag = (k0 >= qt * 128);
#pragma unroll
    for (int q2 = 0; q2 < 2; q2++) {
      if (diag) {
        const int qg = qt * 128 + wq * 32 + q2 * 16 + lr;
#pragma unroll
        for (int kvf = 0; kvf < 4; kvf++)
#pragma unroll
          for (int r = 0; r < 4; r++)
            if (k0 + kvf * 16 + 4 * lg + r > qg) st[kvf][q2][r] = -3e38f;
      }
      float mx = -3e38f;
#pragma unroll
      for (int kvf = 0; kvf < 4; kvf++)
        mx = fmaxf(mx, fmaxf(fmaxf(st[kvf][q2][0], st[kvf][q2][1]),
                             fmaxf(st[kvf][q2][2], st[kvf][q2][3])));
      mx = fmaxf(mx, __shfl_xor(mx, 16));
      mx = fmaxf(mx, __shfl_xor(mx, 32));
      float mnew = fmaxf(m_[q2], mx);
      float alpha = EXP2((m_[q2] - mnew) * CL2E);
      m_[q2] = mnew;
      float nmc = -mnew * CL2E;
      float rs = 0.f;
      const int prow = wq * 32 + q2 * 16 + lr;
#pragma unroll
      for (int kvf = 0; kvf < 4; kvf++) {
        float p0 = EXP2(fmaf(st[kvf][q2][0], CL2E, nmc));
        float p1 = EXP2(fmaf(st[kvf][q2][1], CL2E, nmc));
        float p2 = EXP2(fmaf(st[kvf][q2][2], CL2E, nmc));
        float p3 = EXP2(fmaf(st[kvf][q2][3], CL2E, nmc));
        rs += (p0 + p1) + (p2 + p3);
        uint2 w;
        w.x = pk2bf(p0, p1);
        w.y = pk2bf(p2, p3);
        *(uint2*)(sP + prow * 128 + ((kvf * 32 + lg * 8) ^ ((prow & 7) << 4))) = w;
      }
      rs += __shfl_xor(rs, 16);
      rs += __shfl_xor(rs, 32);
      l_[q2] = l_[q2] * alpha + rs;
#pragma unroll
      for (int df = 0; df < 4; df++) ot[df][q2] *= alpha;
    }

    // ---- O^T += V^T · P^T (wave-local sP traffic, no barrier) ----
#pragma unroll
    for (int kf = 0; kf < 2; kf++) {
      bf16x8 pf[2], vf[4];
#pragma unroll
      for (int q2 = 0; q2 < 2; q2++) {
        int row = wq * 32 + q2 * 16 + lr;
        pf[q2] = *(const bf16x8*)(sP + row * 128 + ((kf * 64 + lg * 16) ^ ((row & 7) << 4)));
      }
#pragma unroll
      for (int df = 0; df < 4; df++) {
        int row = df * 16 + lr;
        vf[df] = *(const bf16x8*)(sV + row * 128 + ((kf * 64 + lg * 16) ^ ((row & 7) << 4)));
      }
#pragma unroll
      for (int df = 0; df < 4; df++)
#pragma unroll
        for (int q2 = 0; q2 < 2; q2++)
          ot[df][q2] = __builtin_amdgcn_mfma_f32_16x16x32_bf16(vf[df], pf[q2], ot[df][q2], 0, 0, 0);
    }
  }

  // ---- normalize + packed store of concat ctx [B,S,H*D] ----
#pragma unroll
  for (int q2 = 0; q2 < 2; q2++) {
    float inv = 1.0f / l_[q2];
    int s = qt * 128 + wq * 32 + q2 * 16 + lr;
#pragma unroll
    for (int df = 0; df < 4; df++) {
      uint2 w;
      w.x = pk2bf(ot[df][q2][0] * inv, ot[df][q2][1] * inv);
      w.y = pk2bf(ot[df][q2][2] * inv, ot[df][q2][3] * inv);
      *(uint2*)(Cc + ((size_t)b * SEQ + s) * (NHEADS * HDIM) + h * HDIM + df * 16 + 4 * lg) = w;
    }
  }
}

// ---------------- GEMM2: ctx[8192x1024] x Wo^T + bo -> out fp32 ----------------
__global__ __launch_bounds__(256) void k_gemm_out(const u16* __restrict__ Cc,
                                                  const u16* __restrict__ Wob,
                                                  const float* __restrict__ bo,
                                                  float* __restrict__ out) {
  const int m0 = blockIdx.x * 128;
  const int n0 = blockIdx.y * 128;
  const int t = threadIdx.x;
  const int wave = t >> 6, lane = t & 63, lr = lane & 15, lg = lane >> 4;
  const int wr = (wave >> 1) * 64, wc = (wave & 1) * 64;

  __shared__ __align__(16) char sA[128 * 128];
  __shared__ __align__(16) char sB[128 * 128];

  const f32x4 fz = {0.f, 0.f, 0.f, 0.f};
  f32x4 acc[4][4];
#pragma unroll
  for (int i = 0; i < 4; i++)
#pragma unroll
    for (int j = 0; j < 4; j++) acc[i][j] = fz;

  for (int k0 = 0; k0 < EMB; k0 += 64) {
#pragma unroll
    for (int i = 0; i < 4; i++) {
      int rb = wave * 32 + i * 8;
      int row = rb + (lane >> 3);
      int gc = (lane & 7) ^ (row & 7);
      gl16(Cc + (size_t)(m0 + row) * EMB + k0 + gc * 8, sA + rb * 128);
      gl16(Wob + (size_t)(n0 + row) * EMB + k0 + gc * 8, sB + rb * 128);
    }
    __syncthreads();
    bf16x8 af[4][2], bfr[4][2];
#pragma unroll
    for (int mf = 0; mf < 4; mf++)
#pragma unroll
      for (int kf = 0; kf < 2; kf++) {
        int row = wr + mf * 16 + lr;
        af[mf][kf] = *(const bf16x8*)(sA + row * 128 + ((kf * 64 + lg * 16) ^ ((row & 7) << 4)));
      }
#pragma unroll
    for (int nf = 0; nf < 4; nf++)
#pragma unroll
      for (int kf = 0; kf < 2; kf++) {
        int row = wc + nf * 16 + lr;
        bfr[nf][kf] = *(const bf16x8*)(sB + row * 128 + ((kf * 64 + lg * 16) ^ ((row & 7) << 4)));
      }
#pragma unroll
    for (int kf = 0; kf < 2; kf++)
#pragma unroll
      for (int mf = 0; mf < 4; mf++)
#pragma unroll
        for (int nf = 0; nf < 4; nf++)
          acc[mf][nf] = __builtin_amdgcn_mfma_f32_16x16x32_bf16(af[mf][kf], bfr[nf][kf], acc[mf][nf], 0, 0, 0);
    __syncthreads();
  }

  float bv[4];
#pragma unroll
  for (int nf = 0; nf < 4; nf++) bv[nf] = bo[n0 + wc + nf * 16 + lr];
#pragma unroll
  for (int mf = 0; mf < 4; mf++)
#pragma unroll
    for (int nf = 0; nf < 4; nf++)
#pragma unroll
      for (int r = 0; r < 4; r++) {
        int row = wr + mf * 16 + lg * 4 + r;
        int n = n0 + wc + nf * 16 + lr;
        out[(size_t)(m0 + row) * EMB + n] = acc[mf][nf][r] + bv[nf];
      }
}

extern "C" void kernel_launch(void* const* d_in, const int* in_sizes, int n_in,
                              void* d_out, int out_size, void* d_ws, size_t ws_size,
                              hipStream_t stream) {
  const float* x  = (const float*)d_in[0];
  const float* Wq = (const float*)d_in[1];
  const float* Wk = (const float*)d_in[2];
  const float* Wv = (const float*)d_in[3];
  const float* Wo = (const float*)d_in[4];
  const float* bo = (const float*)d_in[5];
  float* out = (float*)d_out;

  char* ws = (char*)d_ws;
  const size_t SZ_XB  = (size_t)8192 * 1024 * 2;
  const size_t SZ_WT  = (size_t)3072 * 1024 * 2;
  const size_t SZ_WOB = (size_t)1024 * 1024 * 2;
  const size_t SZ_QKV = (size_t)64 * 2048 * 64 * 2;
  u16* Xb  = (u16*)(ws);
  u16* Wt  = (u16*)(ws + SZ_XB);
  u16* Wob = (u16*)(ws + SZ_XB + SZ_WT);
  u16* Qb  = (u16*)(ws + SZ_XB + SZ_WT + SZ_WOB);
  u16* Kb  = (u16*)(ws + SZ_XB + SZ_WT + SZ_WOB + SZ_QKV);
  u16* Vb  = (u16*)(ws + SZ_XB + SZ_WT + SZ_WOB + 2 * SZ_QKV);
  u16* Cc  = (u16*)(ws + SZ_XB + SZ_WT + SZ_WOB + 3 * SZ_QKV);

  k_cvt<<<8192, 256, 0, stream>>>(x, Xb, 2097152);
  k_cvt<<<1024, 256, 0, stream>>>(Wo, Wob, 262144);
  k_packw<<<dim3(48, 16), 256, 0, stream>>>(Wq, Wk, Wv, Wt);
  k_gemm_qkv<<<dim3(64, 24), 256, 0, stream>>>(Xb, Wt, Qb, Kb, Vb);
  k_attn<<<dim3(64, 16), 256, 0, stream>>>(Qb, Kb, Vb, Cc);
  k_gemm_out<<<dim3(64, 8), 256, 0, stream>>>(Cc, Wob, bo, out);
}

// Round 3
// 172.242 us; speedup vs baseline: 1.5757x; 1.0110x over previous
//
#include <hip/hip_runtime.h>

#define NHEADS 16
#define EMB 1024
#define HDIM 64
#define SEQ 2048
#define BATCH 4

typedef unsigned short u16;
typedef __attribute__((ext_vector_type(8))) __bf16 bf16x8;
typedef __attribute__((ext_vector_type(4))) float f32x4;

#if __has_builtin(__builtin_amdgcn_exp2f)
#define EXP2(x) __builtin_amdgcn_exp2f(x)
#else
#define EXP2(x) __expf((x)*0.69314718056f)
#endif
#define CL2E 0.18033688011112042f  // 0.125 * log2(e)

#define BARRIER() __builtin_amdgcn_s_barrier()
#define SB0() __builtin_amdgcn_sched_barrier(0)
#define PRIO1() __builtin_amdgcn_s_setprio(1)
#define PRIO0() __builtin_amdgcn_s_setprio(0)
#define VMCNT(n) asm volatile("s_waitcnt vmcnt(" #n ")" ::: "memory")

__device__ __forceinline__ u16 f2bf(float f) {
  union { float f; unsigned u; } v; v.f = f;
  unsigned r = v.u + 0x7fffu + ((v.u >> 16) & 1u);
  return (u16)(r >> 16);
}
__device__ __forceinline__ unsigned pk2bf(float a, float b) {
  union { __bf16 h[2]; unsigned u; } x;
  x.h[0] = (__bf16)a; x.h[1] = (__bf16)b; return x.u;
}
__device__ __forceinline__ void gl16(const void* g, void* l) {
  __builtin_amdgcn_global_load_lds(
      (const __attribute__((address_space(1))) unsigned*)g,
      (__attribute__((address_space(3))) unsigned*)l, 16, 0, 0);
}

// ---------------- elementwise f32 -> bf16 ----------------
__global__ __launch_bounds__(256) void k_cvt(const float* __restrict__ in,
                                             u16* __restrict__ out, int n4) {
  int i = blockIdx.x * 256 + threadIdx.x;
  if (i >= n4) return;
  f32x4 v = *(const f32x4*)(in + (size_t)i * 4);
  uint2 o;
  o.x = (unsigned)f2bf(v[0]) | ((unsigned)f2bf(v[1]) << 16);
  o.y = (unsigned)f2bf(v[2]) | ((unsigned)f2bf(v[3]) << 16);
  *(uint2*)(out + (size_t)i * 4) = o;
}

// ---------------- pack Wq/Wk/Wv -> Wt[n=(m,h,d)][k=e] bf16 (transposed) ----------------
__global__ __launch_bounds__(256) void k_packw(const float* __restrict__ Wq,
                                               const float* __restrict__ Wk,
                                               const float* __restrict__ Wv,
                                               u16* __restrict__ Wt) {
  const int mh = blockIdx.x;        // 0..47 = mtx*16+h
  const int e0 = blockIdx.y * 64;
  const int mtx = mh >> 4, h = mh & 15;
  const float* W = (mtx == 0 ? Wq : (mtx == 1 ? Wk : Wv)) + (size_t)h * EMB * HDIM;
  __shared__ u16 sT[64][65];
  const int t = threadIdx.x;
  {
    int e = t >> 2, d0 = (t & 3) * 16;
#pragma unroll
    for (int jj = 0; jj < 4; jj++) {
      f32x4 v = *(const f32x4*)(W + (size_t)(e0 + e) * HDIM + d0 + jj * 4);
#pragma unroll
      for (int kk = 0; kk < 4; kk++) sT[e][d0 + jj * 4 + kk] = f2bf(v[kk]);
    }
  }
  __syncthreads();
  {
    int d = t >> 2, eb = (t & 3) * 16;
#pragma unroll
    for (int j = 0; j < 16; j++)
      Wt[(size_t)(mh * 64 + d) * EMB + e0 + eb + j] = sT[eb + j][d];
  }
}

// ---------------- GEMM1 (8-phase-style, 256x192 tile, counted vmcnt) ----------------
// Xb[8192x1024] x Wt[3072x1024]^T -> Q,K,V [B,H,S,D] bf16
__global__ __launch_bounds__(512, 2) void k_gemm_qkv8(const u16* __restrict__ Xb,
                                                      const u16* __restrict__ Wt,
                                                      u16* __restrict__ Q,
                                                      u16* __restrict__ K,
                                                      u16* __restrict__ V) {
  extern __shared__ __align__(16) char smem[];  // 2 bufs x (A 32KB + B 24KB) = 112KB
  const int bid = blockIdx.x;
  const int l = (bid & 7) * 64 + (bid >> 3);    // XCD-bijective swizzle (512%8==0)
  const int mt = l & 31, nt = l >> 5;
  const int m0 = mt * 256, n0 = nt * 192;

  const int t = threadIdx.x;
  const int wave = t >> 6, lane = t & 63, lr = lane & 15, lg = lane >> 4;
  const int wr = (wave >> 2) * 128;             // 2 M-groups of 128
  const int wc = (wave & 3) * 48;               // 4 N-groups of 48

  const f32x4 fz = {0.f, 0.f, 0.f, 0.f};
  f32x4 acc[8][3];
#pragma unroll
  for (int i = 0; i < 8; i++)
#pragma unroll
    for (int j = 0; j < 3; j++) acc[i][j] = fz;

  bf16x8 af[4][2], bfr[3][2];

  // one staging round: 512 threads x 16B = 8KB = 64 rows of 128B
  auto SROUND = [&](char* ldsbase, int rbase, const u16* src, int gRowBase, int kt) {
    int rs = rbase + wave * 8;
    int row = rs + (lane >> 3);
    int gc = (lane & 7) ^ (row & 7);
    gl16(src + (size_t)(gRowBase + row) * EMB + kt * 64 + gc * 8, ldsbase + rs * 128);
  };
  auto LOADA = [&](const char* bA, int mh) {
#pragma unroll
    for (int mf = 0; mf < 4; mf++)
#pragma unroll
      for (int kf = 0; kf < 2; kf++) {
        int row = wr + mh * 64 + mf * 16 + lr;
        af[mf][kf] = *(const bf16x8*)(bA + row * 128 + ((kf * 64 + lg * 16) ^ ((row & 7) << 4)));
      }
  };
  auto LOADB = [&](const char* bB) {
#pragma unroll
    for (int nf = 0; nf < 3; nf++)
#pragma unroll
      for (int kf = 0; kf < 2; kf++) {
        int row = wc + nf * 16 + lr;
        bfr[nf][kf] = *(const bf16x8*)(bB + row * 128 + ((kf * 64 + lg * 16) ^ ((row & 7) << 4)));
      }
  };

#define MFMAPH(MH)                                                                         \
  do {                                                                                     \
    _Pragma("unroll") for (int kf = 0; kf < 2; kf++)                                       \
    _Pragma("unroll") for (int mf = 0; mf < 4; mf++)                                       \
    _Pragma("unroll") for (int nf = 0; nf < 3; nf++)                                       \
      acc[(MH)*4 + mf][nf] = __builtin_amdgcn_mfma_f32_16x16x32_bf16(                      \
          af[mf][kf], bfr[nf][kf], acc[(MH)*4 + mf][nf], 0, 0, 0);                         \
  } while (0)

  const int NT = EMB / 64;  // 16 K-tiles
  // prologue: stage tile 0 fully (7 rounds), drain, barrier
  {
    char* nA = smem;
    char* nB = smem + 32768;
    SROUND(nB, 0, Wt, n0, 0); SROUND(nB, 64, Wt, n0, 0); SROUND(nB, 128, Wt, n0, 0);
    SROUND(nA, 0, Xb, m0, 0);
    SROUND(nA, 64, Xb, m0, 0); SROUND(nA, 128, Xb, m0, 0); SROUND(nA, 192, Xb, m0, 0);
  }
  VMCNT(0);
  BARRIER();

  for (int tt = 0; tt < NT - 1; tt++) {
    const int cb = tt & 1, nb = cb ^ 1;
    char* bA = smem + cb * 57344;
    char* bB = bA + 32768;
    char* nA = smem + nb * 57344;
    char* nB = nA + 32768;
    // ---- phase 0: stage B0,B1,B2,ALo0 of t+1; read A-lo + B of t; MFMA mh=0 ----
    SROUND(nB, 0, Wt, n0, tt + 1);
    SROUND(nB, 64, Wt, n0, tt + 1);
    SROUND(nB, 128, Wt, n0, tt + 1);
    SROUND(nA, 0, Xb, m0, tt + 1);
    LOADA(bA, 0);
    LOADB(bB);
    VMCNT(4);                       // retire AHi0,AHi1(t) -> safe for phase 1 reads
    BARRIER(); SB0();
    PRIO1(); MFMAPH(0); PRIO0();
    BARRIER();
    // ---- phase 1: stage ALo1,AHi0,AHi1 of t+1; read A-hi of t; MFMA mh=1 ----
    SROUND(nA, 64, Xb, m0, tt + 1);
    SROUND(nA, 128, Xb, m0, tt + 1);
    SROUND(nA, 192, Xb, m0, tt + 1);
    LOADA(bA, 1);
    VMCNT(2);                       // retire B0..ALo1(t+1) -> safe for next phase 0
    BARRIER(); SB0();
    PRIO1(); MFMAPH(1); PRIO0();
    BARRIER();
  }
  // ---- epilogue tile NT-1 (buf 1), no staging ----
  {
    char* bA = smem + ((NT - 1) & 1) * 57344;
    char* bB = bA + 32768;
    LOADA(bA, 0);
    LOADB(bB);
    VMCNT(0);                       // retire AHi(NT-1)
    BARRIER(); SB0();
    PRIO1(); MFMAPH(0); PRIO0();
    LOADA(bA, 1);
    PRIO1(); MFMAPH(1); PRIO0();
  }
#undef MFMAPH

  // ---- C write: scatter into Q/K/V [B,H,S,D] ----
  const int b = m0 >> 11;
  const int s0 = m0 & 2047;
#pragma unroll
  for (int am = 0; am < 8; am++)
#pragma unroll
    for (int nf = 0; nf < 3; nf++)
#pragma unroll
      for (int r = 0; r < 4; r++) {
        int row = wr + am * 16 + lg * 4 + r;
        int n = n0 + wc + nf * 16 + lr;
        int mtx = n >> 10, h = (n >> 6) & 15, d = n & 63;
        u16* dst = (mtx == 0 ? Q : (mtx == 1 ? K : V));
        dst[((size_t)(b * NHEADS + h) * SEQ + s0 + row) * HDIM + d] = f2bf(acc[am][nf][r]);
      }
}

// ---------------- causal flash attention (swapped QK^T / transposed PV) ----------------
__global__ __launch_bounds__(256, 3) void k_attn(const u16* __restrict__ Q,
                                                 const u16* __restrict__ K,
                                                 const u16* __restrict__ V,
                                                 u16* __restrict__ Cc) {
  const int bh = blockIdx.x;                 // 0..63
  const int qt = 15 - (int)blockIdx.y;       // LPT: heaviest q-tiles dispatched first
  const int b = bh >> 4, h = bh & 15;
  const int t = threadIdx.x;
  const int wq = t >> 6, lane = t & 63, lr = lane & 15, lg = lane >> 4;
  const size_t base = (size_t)bh * SEQ * HDIM;

  __shared__ __align__(16) char sK[64 * 128];
  __shared__ __align__(16) char sV[64 * 128];
  __shared__ __align__(16) char sP[128 * 128];

  // ---- stage Q tile (swizzled, via global_load_lds) ----
#pragma unroll
  for (int i = 0; i < 4; i++) {
    int rb = wq * 32 + i * 8;
    int row = rb + (lane >> 3);
    int gc = (lane & 7) ^ (row & 7);
    gl16(Q + base + (size_t)(qt * 128 + row) * HDIM + gc * 8, sP + rb * 128);
  }
  __syncthreads();
  bf16x8 qf[2][2];
#pragma unroll
  for (int q2 = 0; q2 < 2; q2++)
#pragma unroll
    for (int kf = 0; kf < 2; kf++) {
      int row = wq * 32 + q2 * 16 + lr;
      qf[q2][kf] = *(const bf16x8*)(sP + row * 128 + ((kf * 64 + lg * 16) ^ ((row & 7) << 4)));
    }

  const f32x4 fz = {0.f, 0.f, 0.f, 0.f};
  f32x4 ot[4][2];  // O^T frags: row d = df*16+4*lg+r, col q = lr
#pragma unroll
  for (int df = 0; df < 4; df++)
#pragma unroll
    for (int q2 = 0; q2 < 2; q2++) ot[df][q2] = fz;
  float m_[2] = {-1e30f, -1e30f}, l_[2] = {0.f, 0.f};

  const int nsteps = 2 * qt + 2;
  for (int step = 0; step < nsteps; step++) {
    const int k0 = step * 64;
    __syncthreads();
    // K stage via global_load_lds (pre-swizzled source)
#pragma unroll
    for (int i = 0; i < 2; i++) {
      int rb = wq * 16 + i * 8;
      int row = rb + (lane >> 3);
      int gc = (lane & 7) ^ (row & 7);
      gl16(K + base + (size_t)(k0 + row) * HDIM + gc * 8, sK + rb * 128);
    }
    // V transposed [d][kv], kv=lane mapping -> 2-way (free) bank pattern
    {
      const int kv = lane, d0 = wq * 16;
      const u16* vp = V + base + (size_t)(k0 + kv) * HDIM + d0;
      bf16x8 v0 = *(const bf16x8*)vp;
      bf16x8 v1 = *(const bf16x8*)(vp + 8);
#pragma unroll
      for (int j = 0; j < 8; j++) {
        int d = d0 + j, d2 = d0 + 8 + j;
        *(__bf16*)(sV + d * 128 + ((kv * 2) ^ ((d & 7) << 4))) = v0[j];
        *(__bf16*)(sV + d2 * 128 + ((kv * 2) ^ ((d2 & 7) << 4))) = v1[j];
      }
    }
    __syncthreads();

    // ---- S^T = K · Q^T  (D: col=q=lr, row=kv=4*lg+r) ----
    f32x4 st[4][2];
#pragma unroll
    for (int kvf = 0; kvf < 4; kvf++)
#pragma unroll
      for (int q2 = 0; q2 < 2; q2++) st[kvf][q2] = fz;
#pragma unroll
    for (int kf = 0; kf < 2; kf++) {
      bf16x8 kfr[4];
#pragma unroll
      for (int kvf = 0; kvf < 4; kvf++) {
        int row = kvf * 16 + lr;
        kfr[kvf] = *(const bf16x8*)(sK + row * 128 + ((kf * 64 + lg * 16) ^ ((row & 7) << 4)));
      }
#pragma unroll
      for (int kvf = 0; kvf < 4; kvf++)
#pragma unroll
        for (int q2 = 0; q2 < 2; q2++)
          st[kvf][q2] = __builtin_amdgcn_mfma_f32_16x16x32_bf16(kfr[kvf], qf[q2][kf], st[kvf][q2], 0, 0, 0);
    }

    // ---- online softmax, row-local (q = lr) ----
    const bool diag = (k0 >= qt * 128);
#pragma unroll
    for (int q2 = 0; q2 < 2; q2++) {
      if (diag) {
        const int qg = qt * 128 + wq * 32 + q2 * 16 + lr;
#pragma unroll
        for (int kvf = 0; kvf < 4; kvf++)
#pragma unroll
          for (int r = 0; r < 4; r++)
            if (k0 + kvf * 16 + 4 * lg + r > qg) st[kvf][q2][r] = -3e38f;
      }
      float mx = -3e38f;
#pragma unroll
      for (int kvf = 0; kvf < 4; kvf++)
        mx = fmaxf(mx, fmaxf(fmaxf(st[kvf][q2][0], st[kvf][q2][1]),
                             fmaxf(st[kvf][q2][2], st[kvf][q2][3])));
      mx = fmaxf(mx, __shfl_xor(mx, 16));
      mx = fmaxf(mx, __shfl_xor(mx, 32));
      float mnew = fmaxf(m_[q2], mx);
      float alpha = EXP2((m_[q2] - mnew) * CL2E);
      m_[q2] = mnew;
      float nmc = -mnew * CL2E;
      float rs = 0.f;
      const int prow = wq * 32 + q2 * 16 + lr;
#pragma unroll
      for (int kvf = 0; kvf < 4; kvf++) {
        float p0 = EXP2(fmaf(st[kvf][q2][0], CL2E, nmc));
        float p1 = EXP2(fmaf(st[kvf][q2][1], CL2E, nmc));
        float p2 = EXP2(fmaf(st[kvf][q2][2], CL2E, nmc));
        float p3 = EXP2(fmaf(st[kvf][q2][3], CL2E, nmc));
        rs += (p0 + p1) + (p2 + p3);
        uint2 w;
        w.x = pk2bf(p0, p1);
        w.y = pk2bf(p2, p3);
        *(uint2*)(sP + prow * 128 + ((kvf * 32 + lg * 8) ^ ((prow & 7) << 4))) = w;
      }
      rs += __shfl_xor(rs, 16);
      rs += __shfl_xor(rs, 32);
      l_[q2] = l_[q2] * alpha + rs;
#pragma unroll
      for (int df = 0; df < 4; df++) ot[df][q2] *= alpha;
    }

    // ---- O^T += V^T · P^T (wave-local sP traffic, no barrier) ----
#pragma unroll
    for (int kf = 0; kf < 2; kf++) {
      bf16x8 pf[2], vf[4];
#pragma unroll
      for (int q2 = 0; q2 < 2; q2++) {
        int row = wq * 32 + q2 * 16 + lr;
        pf[q2] = *(const bf16x8*)(sP + row * 128 + ((kf * 64 + lg * 16) ^ ((row & 7) << 4)));
      }
#pragma unroll
      for (int df = 0; df < 4; df++) {
        int row = df * 16 + lr;
        vf[df] = *(const bf16x8*)(sV + row * 128 + ((kf * 64 + lg * 16) ^ ((row & 7) << 4)));
      }
#pragma unroll
      for (int df = 0; df < 4; df++)
#pragma unroll
        for (int q2 = 0; q2 < 2; q2++)
          ot[df][q2] = __builtin_amdgcn_mfma_f32_16x16x32_bf16(vf[df], pf[q2], ot[df][q2], 0, 0, 0);
    }
  }

  // ---- normalize + packed store of concat ctx [B,S,H*D] ----
#pragma unroll
  for (int q2 = 0; q2 < 2; q2++) {
    float inv = 1.0f / l_[q2];
    int s = qt * 128 + wq * 32 + q2 * 16 + lr;
#pragma unroll
    for (int df = 0; df < 4; df++) {
      uint2 w;
      w.x = pk2bf(ot[df][q2][0] * inv, ot[df][q2][1] * inv);
      w.y = pk2bf(ot[df][q2][2] * inv, ot[df][q2][3] * inv);
      *(uint2*)(Cc + ((size_t)b * SEQ + s) * (NHEADS * HDIM) + h * HDIM + df * 16 + 4 * lg) = w;
    }
  }
}

// ---------------- GEMM2: ctx[8192x1024] x Wo^T + bo -> out fp32 ----------------
__global__ __launch_bounds__(256) void k_gemm_out(const u16* __restrict__ Cc,
                                                  const u16* __restrict__ Wob,
                                                  const float* __restrict__ bo,
                                                  float* __restrict__ out) {
  const int m0 = blockIdx.x * 128;
  const int n0 = blockIdx.y * 128;
  const int t = threadIdx.x;
  const int wave = t >> 6, lane = t & 63, lr = lane & 15, lg = lane >> 4;
  const int wr = (wave >> 1) * 64, wc = (wave & 1) * 64;

  __shared__ __align__(16) char sA[128 * 128];
  __shared__ __align__(16) char sB[128 * 128];

  const f32x4 fz = {0.f, 0.f, 0.f, 0.f};
  f32x4 acc[4][4];
#pragma unroll
  for (int i = 0; i < 4; i++)
#pragma unroll
    for (int j = 0; j < 4; j++) acc[i][j] = fz;

  for (int k0 = 0; k0 < EMB; k0 += 64) {
#pragma unroll
    for (int i = 0; i < 4; i++) {
      int rb = wave * 32 + i * 8;
      int row = rb + (lane >> 3);
      int gc = (lane & 7) ^ (row & 7);
      gl16(Cc + (size_t)(m0 + row) * EMB + k0 + gc * 8, sA + rb * 128);
      gl16(Wob + (size_t)(n0 + row) * EMB + k0 + gc * 8, sB + rb * 128);
    }
    __syncthreads();
    bf16x8 af[4][2], bfr[4][2];
#pragma unroll
    for (int mf = 0; mf < 4; mf++)
#pragma unroll
      for (int kf = 0; kf < 2; kf++) {
        int row = wr + mf * 16 + lr;
        af[mf][kf] = *(const bf16x8*)(sA + row * 128 + ((kf * 64 + lg * 16) ^ ((row & 7) << 4)));
      }
#pragma unroll
    for (int nf = 0; nf < 4; nf++)
#pragma unroll
      for (int kf = 0; kf < 2; kf++) {
        int row = wc + nf * 16 + lr;
        bfr[nf][kf] = *(const bf16x8*)(sB + row * 128 + ((kf * 64 + lg * 16) ^ ((row & 7) << 4)));
      }
#pragma unroll
    for (int kf = 0; kf < 2; kf++)
#pragma unroll
      for (int mf = 0; mf < 4; mf++)
#pragma unroll
        for (int nf = 0; nf < 4; nf++)
          acc[mf][nf] = __builtin_amdgcn_mfma_f32_16x16x32_bf16(af[mf][kf], bfr[nf][kf], acc[mf][nf], 0, 0, 0);
    __syncthreads();
  }

  float bv[4];
#pragma unroll
  for (int nf = 0; nf < 4; nf++) bv[nf] = bo[n0 + wc + nf * 16 + lr];
#pragma unroll
  for (int mf = 0; mf < 4; mf++)
#pragma unroll
    for (int nf = 0; nf < 4; nf++)
#pragma unroll
      for (int r = 0; r < 4; r++) {
        int row = wr + mf * 16 + lg * 4 + r;
        int n = n0 + wc + nf * 16 + lr;
        out[(size_t)(m0 + row) * EMB + n] = acc[mf][nf][r] + bv[nf];
      }
}

extern "C" void kernel_launch(void* const* d_in, const int* in_sizes, int n_in,
                              void* d_out, int out_size, void* d_ws, size_t ws_size,
                              hipStream_t stream) {
  const float* x  = (const float*)d_in[0];
  const float* Wq = (const float*)d_in[1];
  const float* Wk = (const float*)d_in[2];
  const float* Wv = (const float*)d_in[3];
  const float* Wo = (const float*)d_in[4];
  const float* bo = (const float*)d_in[5];
  float* out = (float*)d_out;

  char* ws = (char*)d_ws;
  const size_t SZ_XB  = (size_t)8192 * 1024 * 2;
  const size_t SZ_WT  = (size_t)3072 * 1024 * 2;
  const size_t SZ_WOB = (size_t)1024 * 1024 * 2;
  const size_t SZ_QKV = (size_t)64 * 2048 * 64 * 2;
  u16* Xb  = (u16*)(ws);
  u16* Wt  = (u16*)(ws + SZ_XB);
  u16* Wob = (u16*)(ws + SZ_XB + SZ_WT);
  u16* Qb  = (u16*)(ws + SZ_XB + SZ_WT + SZ_WOB);
  u16* Kb  = (u16*)(ws + SZ_XB + SZ_WT + SZ_WOB + SZ_QKV);
  u16* Vb  = (u16*)(ws + SZ_XB + SZ_WT + SZ_WOB + 2 * SZ_QKV);
  u16* Cc  = (u16*)(ws + SZ_XB + SZ_WT + SZ_WOB + 3 * SZ_QKV);

  k_cvt<<<8192, 256, 0, stream>>>(x, Xb, 2097152);
  k_cvt<<<1024, 256, 0, stream>>>(Wo, Wob, 262144);
  k_packw<<<dim3(48, 16), 256, 0, stream>>>(Wq, Wk, Wv, Wt);
  k_gemm_qkv8<<<512, 512, 114688, stream>>>(Xb, Wt, Qb, Kb, Vb);
  k_attn<<<dim3(64, 16), 256, 0, stream>>>(Qb, Kb, Vb, Cc);
  k_gemm_out<<<dim3(64, 8), 256, 0, stream>>>(Cc, Wob, bo, out);
}